// Round 6
// baseline (686.656 us; speedup 1.0000x reference)
//
#include <hip/hip_runtime.h>
#include <hip/hip_bf16.h>

#define P_TOTAL 160000
#define NPB     40000      // points per batch (B=4)
#define NCLS    13
#define TP      32         // points per block (2 m-tiles per wave: small reg footprint)
#define NBLK    (P_TOTAL / TP)   // 5000

typedef __attribute__((ext_vector_type(8))) short bf16x8;   // 8 bf16 in 4 VGPRs
typedef __attribute__((ext_vector_type(4))) float f32x4;

__device__ __forceinline__ ushort f2bf(float f) {
  union { float f; unsigned u; } v; v.f = f;
  return (ushort)((v.u + 0x8000) >> 16);   // round-to-nearest (ties away)
}

// ---------------- fused prep: transposes + WT1 + histogram ----------------
__device__ __forceinline__ void transpose_tile(const float* __restrict__ src,
                                               ushort* __restrict__ dst,
                                               int K, int N, int tile, ushort (*t)[33]) {
  int ntx = N >> 5;
  int n0 = (tile % ntx) << 5, k0 = (tile / ntx) << 5;
  int c = threadIdx.x & 31, r = threadIdx.x >> 5;   // 8 rows of 32
  #pragma unroll
  for (int rr = 0; rr < 32; rr += 8)
    t[r + rr][c] = f2bf(src[(k0 + r + rr) * N + n0 + c]);
  __syncthreads();
  #pragma unroll
  for (int rr = 0; rr < 32; rr += 8)
    dst[(n0 + r + rr) * K + k0 + c] = t[c][r + rr];
}

__global__ void prep_all_kernel(const float* __restrict__ We1, const float* __restrict__ We2,
                                const float* __restrict__ W1,  const float* __restrict__ W2,
                                const int* __restrict__ y,
                                ushort* __restrict__ WT1, ushort* __restrict__ WT2,
                                ushort* __restrict__ WT3, ushort* __restrict__ WT4,
                                int* __restrict__ counts) {
  __shared__ ushort t[32][33];
  __shared__ int h[NCLS];
  int b = blockIdx.x, tid = threadIdx.x;
  if (b < 128)       transpose_tile(We2, WT2, 256, 512, b, t);
  else if (b < 256)  transpose_tile(W1,  WT3, 512, 256, b - 128, t);
  else if (b < 288)  transpose_tile(W2,  WT4, 256, 128, b - 256, t);
  else if (b == 288) {
    for (int i = tid; i < 8192; i += 256) {        // WT1: [256][32], k<7 real
      int n = i >> 5, k = i & 31;
      WT1[i] = (k < 7) ? f2bf(We1[k * 256 + n]) : (ushort)0;
    }
  } else {
    if (tid < NCLS) h[tid] = 0;
    __syncthreads();
    for (int i = (b - 289) * 256 + tid; i < P_TOTAL; i += 127 * 256)
      atomicAdd(&h[y[i]], 1);
    __syncthreads();
    if (tid < NCLS) atomicAdd(&counts[tid], h[tid]);
  }
}

// ---------------- fused MLP + norm + output + class sums + last-block finalize ----------------
// Layouts (measured m89/m91): A[m=lane&15][k=quad*8+j]; B[n=lane&15][k=quad*8+j];
// C/D: col=lane&15, row=quad*4+reg.
// TP=32 -> 2 m-tiles/wave: live set ~acc3(16)+acc2(8)+af(8)+bw+addr ~= 60 regs.
// launch_bounds(512,6): cap 85 regs — above live set, no spill expected.
// (round 4 lesson: never bound below the live set — VGPR=40 caused 9x HBM spill traffic)
__global__ __launch_bounds__(512, 6) void main_kernel(
    const float* __restrict__ pos, const float* __restrict__ x, const int* __restrict__ y,
    const float* __restrict__ be1, const float* __restrict__ be2,
    const float* __restrict__ b1,  const float* __restrict__ b2,
    const ushort* __restrict__ WT1, const ushort* __restrict__ WT2,
    const ushort* __restrict__ WT3, const ushort* __restrict__ WT4,
    const int* __restrict__ counts, float* __restrict__ gsums, int* __restrict__ done,
    const float* __restrict__ prior, float* __restrict__ out) {
  __shared__ ushort actbuf[TP * 264];     // 16896 B: act1 [32][256+8], later act3
  __shared__ ushort chunkbuf[TP * 136];   //  8704 B: A0 [32][40] -> act2 chunks [32][128+8]
  __shared__ float  part[8 * TP];         //  1024 B
  __shared__ float  inv_norm[TP];
  __shared__ float  lbl_eff[TP];
  __shared__ int    lbl[TP];
  __shared__ float  invn[NCLS];
  __shared__ int    is_last;

  const int tid  = threadIdx.x;
  const int wave = tid >> 6, lane = tid & 63;
  const int quad = lane >> 4, mrow = lane & 15;
  const long p0 = (long)blockIdx.x * TP;   // 40000 % 32 == 0: block never spans batches
  const int bb = (int)(p0 / NPB);
  const int n0 = (int)(p0 % NPB);
  const f32x4 zero = {0.f, 0.f, 0.f, 0.f};

  // ---- stage A0 = [x(4) | pos(3) | 0...] bf16, stride 40 ----
  for (int i = tid; i < TP * 40; i += 512) {
    int r = i / 40, k = i - r * 40;
    float v = 0.f;
    if (k < 4)      v = x[(bb * 4 + k) * NPB + n0 + r];
    else if (k < 7) v = pos[(p0 + r) * 3 + (k - 4)];
    chunkbuf[r * 40 + k] = f2bf(v);
  }
  if (tid < TP) lbl[tid] = y[p0 + tid];
  __syncthreads();

  // ---- L1: [32x32] @ WT1[256][32]^T -> act1; wave cols wave*32 + nt*16 ----
  {
    f32x4 acc1[2][2];
    #pragma unroll
    for (int mt = 0; mt < 2; mt++) { acc1[mt][0] = zero; acc1[mt][1] = zero; }
    const int kl = quad << 3;
    bf16x8 af[2], bw[2];
    #pragma unroll
    for (int mt = 0; mt < 2; mt++)
      af[mt] = *(const bf16x8*)(chunkbuf + (mt * 16 + mrow) * 40 + kl);
    #pragma unroll
    for (int nt = 0; nt < 2; nt++)
      bw[nt] = *(const bf16x8*)(WT1 + (wave * 32 + nt * 16 + mrow) * 32 + kl);
    #pragma unroll
    for (int nt = 0; nt < 2; nt++)
      #pragma unroll
      for (int mt = 0; mt < 2; mt++)
        acc1[mt][nt] = __builtin_amdgcn_mfma_f32_16x16x32_bf16(af[mt], bw[nt], acc1[mt][nt], 0, 0, 0);
    #pragma unroll
    for (int nt = 0; nt < 2; nt++) {
      int n = wave * 32 + nt * 16 + mrow;
      float bv = be1[n];
      #pragma unroll
      for (int mt = 0; mt < 2; mt++)
        #pragma unroll
        for (int r = 0; r < 4; r++)
          actbuf[(mt * 16 + quad * 4 + r) * 264 + n] = f2bf(fmaxf(acc1[mt][nt][r] + bv, 0.f));
    }
  }
  __syncthreads();

  // ---- fused L2+L3: act2 in 4 chunks of 128 cols; acc3 in regs ----
  f32x4 acc3[2][2];
  #pragma unroll
  for (int mt = 0; mt < 2; mt++) { acc3[mt][0] = zero; acc3[mt][1] = zero; }

  for (int c = 0; c < 4; c++) {
    // L2: wave computes act2 chunk-local cols [wave*16, +16)
    f32x4 acc2[2];
    acc2[0] = zero; acc2[1] = zero;
    #pragma unroll
    for (int ks = 0; ks < 8; ks++) {
      const int kl = ks * 32 + (quad << 3);
      bf16x8 af[2];
      #pragma unroll
      for (int mt = 0; mt < 2; mt++)
        af[mt] = *(const bf16x8*)(actbuf + (mt * 16 + mrow) * 264 + kl);
      bf16x8 bw = *(const bf16x8*)(WT2 + (long)(c * 128 + wave * 16 + mrow) * 256 + kl);
      #pragma unroll
      for (int mt = 0; mt < 2; mt++)
        acc2[mt] = __builtin_amdgcn_mfma_f32_16x16x32_bf16(af[mt], bw, acc2[mt], 0, 0, 0);
    }
    if (c) __syncthreads();                 // prev chunk's readers done (c=0 covered by act1 barrier)
    {
      int lc = wave * 16 + mrow;            // chunk-local col
      float bv = be2[c * 128 + lc];
      #pragma unroll
      for (int mt = 0; mt < 2; mt++)
        #pragma unroll
        for (int r = 0; r < 4; r++)
          chunkbuf[(mt * 16 + quad * 4 + r) * 136 + lc] = f2bf(fmaxf(acc2[mt][r] + bv, 0.f));
    }
    __syncthreads();
    // L3 accumulate over this chunk's 128 k values; wave cols wave*32 + nt*16
    #pragma unroll
    for (int ks = 0; ks < 4; ks++) {
      const int kl = ks * 32 + (quad << 3);
      bf16x8 af[2], bw[2];
      #pragma unroll
      for (int mt = 0; mt < 2; mt++)
        af[mt] = *(const bf16x8*)(chunkbuf + (mt * 16 + mrow) * 136 + kl);
      #pragma unroll
      for (int nt = 0; nt < 2; nt++)
        bw[nt] = *(const bf16x8*)(WT3 + (long)(wave * 32 + nt * 16 + mrow) * 512 + c * 128 + kl);
      #pragma unroll
      for (int nt = 0; nt < 2; nt++)
        #pragma unroll
        for (int mt = 0; mt < 2; mt++)
          acc3[mt][nt] = __builtin_amdgcn_mfma_f32_16x16x32_bf16(af[mt], bw[nt], acc3[mt][nt], 0, 0, 0);
    }
  }

  // ---- L3 epilogue -> act3 into actbuf ----
  #pragma unroll
  for (int nt = 0; nt < 2; nt++) {
    int n = wave * 32 + nt * 16 + mrow;
    float bv = b1[n];
    #pragma unroll
    for (int mt = 0; mt < 2; mt++)
      #pragma unroll
      for (int r = 0; r < 4; r++)
        actbuf[(mt * 16 + quad * 4 + r) * 264 + n] = f2bf(fmaxf(acc3[mt][nt][r] + bv, 0.f));
  }
  __syncthreads();

  // ---- L4: wave col = wave*16 + mrow; feat stays in registers ----
  f32x4 acc4[2];
  acc4[0] = zero; acc4[1] = zero;
  #pragma unroll
  for (int ks = 0; ks < 8; ks++) {
    const int kl = ks * 32 + (quad << 3);
    bf16x8 af[2];
    #pragma unroll
    for (int mt = 0; mt < 2; mt++)
      af[mt] = *(const bf16x8*)(actbuf + (mt * 16 + mrow) * 264 + kl);
    bf16x8 bw = *(const bf16x8*)(WT4 + (long)(wave * 16 + mrow) * 256 + kl);
    #pragma unroll
    for (int mt = 0; mt < 2; mt++)
      acc4[mt] = __builtin_amdgcn_mfma_f32_16x16x32_bf16(af[mt], bw, acc4[mt], 0, 0, 0);
  }
  const int col = wave * 16 + mrow;
  float val[2][4];
  {
    float bv = b2[col];
    #pragma unroll
    for (int mt = 0; mt < 2; mt++)
      #pragma unroll
      for (int r = 0; r < 4; r++)
        val[mt][r] = fmaxf(acc4[mt][r] + bv, 0.f);
  }

  // ---- row-norm partials via quad shfl ----
  #pragma unroll
  for (int mt = 0; mt < 2; mt++)
    #pragma unroll
    for (int r = 0; r < 4; r++) {
      float s = val[mt][r] * val[mt][r];
      s += __shfl_xor(s, 1);  s += __shfl_xor(s, 2);
      s += __shfl_xor(s, 4);  s += __shfl_xor(s, 8);
      if (mrow == 0) part[wave * TP + mt * 16 + quad * 4 + r] = s;
    }
  __syncthreads();
  if (tid < TP) {
    float ss = 0.f;
    #pragma unroll
    for (int w = 0; w < 8; w++) ss += part[w * TP + tid];
    inv_norm[tid] = 1.f / fmaxf(sqrtf(ss), 1e-12f);
    int l = lbl[tid];
    lbl_eff[tid] = (counts[l] >= 256) ? (float)l : -1.f;   // MIN_PTS gate
  }
  __syncthreads();

  // ---- store current_prior from regs + per-class sums ----
  float a[NCLS];
  #pragma unroll
  for (int cc = 0; cc < NCLS; cc++) a[cc] = 0.f;
  #pragma unroll
  for (int mt = 0; mt < 2; mt++)
    #pragma unroll
    for (int r = 0; r < 4; r++) {
      int R = mt * 16 + quad * 4 + r;
      float vn = val[mt][r] * inv_norm[R];
      out[(p0 + R) * 129 + col] = vn;
      int cls = lbl[R];
      #pragma unroll
      for (int cc = 0; cc < NCLS; cc++) a[cc] += (cls == cc) ? vn : 0.f;
    }
  if (tid < TP) out[(p0 + tid) * 129 + 128] = lbl_eff[tid];
  #pragma unroll
  for (int cc = 0; cc < NCLS; cc++) {
    a[cc] += __shfl_xor(a[cc], 16);
    a[cc] += __shfl_xor(a[cc], 32);
  }
  if (quad == 0)
    #pragma unroll
    for (int cc = 0; cc < NCLS; cc++) atomicAdd(&gsums[cc * 128 + col], a[cc]);

  // ---- last block finalizes the EMA prior (saves a dispatch) ----
  __syncthreads();                         // all waves' gsums atomics issued
  if (tid == 0) {
    __threadfence();                       // device-scope release
    int old = atomicAdd(done, 1);
    is_last = (old == NBLK - 1);
  }
  __syncthreads();
  if (!is_last) return;

  float* vbuf = (float*)actbuf;            // actbuf dead; 6656 B needed
  for (int i = tid; i < NCLS * 128; i += 512) {
    float g = atomicAdd(&gsums[i], 0.f);   // coherent device-scope read
    int cls = i >> 7;
    int cnt = counts[cls];
    float mean = g / fmaxf((float)cnt, 1.f);
    float pr = prior[i];
    float cur = (cnt >= 256) ? mean : pr;
    vbuf[i] = 0.999f * pr + 0.001f * cur;
  }
  __syncthreads();
  if (tid < NCLS) {
    float s = 0.f;
    for (int c = 0; c < 128; c++) { float t = vbuf[tid * 128 + c]; s += t * t; }
    invn[tid] = 1.f / fmaxf(sqrtf(s), 1e-12f);
  }
  __syncthreads();
  for (int i = tid; i < NCLS * 128; i += 512)
    out[(long)P_TOTAL * 129 + i] = vbuf[i] * invn[i >> 7];
}

extern "C" void kernel_launch(void* const* d_in, const int* in_sizes, int n_in,
                              void* d_out, int out_size, void* d_ws, size_t ws_size,
                              hipStream_t stream) {
  const float* pos   = (const float*)d_in[0];
  const float* x     = (const float*)d_in[1];
  const int*   y     = (const int*)  d_in[2];
  const float* We1   = (const float*)d_in[3];
  const float* be1   = (const float*)d_in[4];
  const float* We2   = (const float*)d_in[5];
  const float* be2   = (const float*)d_in[6];
  const float* W1    = (const float*)d_in[7];
  const float* b1    = (const float*)d_in[8];
  const float* W2    = (const float*)d_in[9];
  const float* b2    = (const float*)d_in[10];
  const float* prior = (const float*)d_in[11];
  float* out = (float*)d_out;

  char* ws = (char*)d_ws;
  int*    counts = (int*)   (ws + 0);        //    64 B
  float*  gsums  = (float*) (ws + 256);      //  6656 B
  int*    done   = (int*)   (ws + 7168);     //     4 B
  ushort* WT1    = (ushort*)(ws + 8192);     // 16384 B  [256][32]
  ushort* WT2    = (ushort*)(ws + 24576);    // 262144 B [512][256]
  ushort* WT3    = (ushort*)(ws + 286720);   // 262144 B [256][512]
  ushort* WT4    = (ushort*)(ws + 548864);   // 65536 B  [128][256]

  hipMemsetAsync(ws, 0, 8192, stream);       // counts + gsums + done
  prep_all_kernel<<<416, 256, 0, stream>>>(We1, We2, W1, W2, y, WT1, WT2, WT3, WT4, counts);
  main_kernel    <<<NBLK, 512, 0, stream>>>(pos, x, y, be1, be2, b1, b2,
                                            WT1, WT2, WT3, WT4, counts, gsums, done, prior, out);
}

// Round 7
// 347.081 us; speedup vs baseline: 1.9784x; 1.9784x over previous
//
#include <hip/hip_runtime.h>
#include <hip/hip_bf16.h>

#define P_TOTAL 160000
#define NPB     40000      // points per batch (B=4)
#define NCLS    13
#define TP      64         // points per block
#define NBLK    (P_TOTAL / TP)   // 2500

typedef __attribute__((ext_vector_type(8))) short bf16x8;   // 8 bf16 in 4 VGPRs
typedef __attribute__((ext_vector_type(4))) float f32x4;

__device__ __forceinline__ ushort f2bf(float f) {
  union { float f; unsigned u; } v; v.f = f;
  return (ushort)((v.u + 0x8000) >> 16);   // round-to-nearest (ties away)
}

// ---------------- fused prep: transposes + WT1 + histogram ----------------
__device__ __forceinline__ void transpose_tile(const float* __restrict__ src,
                                               ushort* __restrict__ dst,
                                               int K, int N, int tile, ushort (*t)[33]) {
  int ntx = N >> 5;
  int n0 = (tile % ntx) << 5, k0 = (tile / ntx) << 5;
  int c = threadIdx.x & 31, r = threadIdx.x >> 5;   // 8 rows of 32
  #pragma unroll
  for (int rr = 0; rr < 32; rr += 8)
    t[r + rr][c] = f2bf(src[(k0 + r + rr) * N + n0 + c]);
  __syncthreads();
  #pragma unroll
  for (int rr = 0; rr < 32; rr += 8)
    dst[(n0 + r + rr) * K + k0 + c] = t[c][r + rr];
}

__global__ void prep_all_kernel(const float* __restrict__ We1, const float* __restrict__ We2,
                                const float* __restrict__ W1,  const float* __restrict__ W2,
                                const int* __restrict__ y,
                                ushort* __restrict__ WT1, ushort* __restrict__ WT2,
                                ushort* __restrict__ WT3, ushort* __restrict__ WT4,
                                int* __restrict__ counts) {
  __shared__ ushort t[32][33];
  __shared__ int h[NCLS];
  int b = blockIdx.x, tid = threadIdx.x;
  if (b < 128)       transpose_tile(We2, WT2, 256, 512, b, t);
  else if (b < 256)  transpose_tile(W1,  WT3, 512, 256, b - 128, t);
  else if (b < 288)  transpose_tile(W2,  WT4, 256, 128, b - 256, t);
  else if (b == 288) {
    for (int i = tid; i < 8192; i += 256) {        // WT1: [256][32], k<7 real
      int n = i >> 5, k = i & 31;
      WT1[i] = (k < 7) ? f2bf(We1[k * 256 + n]) : (ushort)0;
    }
  } else {
    if (tid < NCLS) h[tid] = 0;
    __syncthreads();
    for (int i = (b - 289) * 256 + tid; i < P_TOTAL; i += 127 * 256)
      atomicAdd(&h[y[i]], 1);
    __syncthreads();
    if (tid < NCLS) atomicAdd(&counts[tid], h[tid]);
  }
}

// ---------------- fused MLP + norm + output + class sums + last-block finalize ----------------
// Layouts (measured m89/m91): A[m=lane&15][k=quad*8+j]; B[n=lane&15][k=quad*8+j];
// C/D: col=lane&15, row=quad*4+reg.
// launch_bounds(512,4): proven config (R3: VGPR=56, no spill, main 261us).
// R4 lesson: (512,6) forces VGPR=40 -> spill -> 9x HBM traffic. R5 lesson: XOR-swizzled
// LDS addressing adds live temps -> spill even at cap 128. Padded strides only.
__global__ __launch_bounds__(512, 4) void main_kernel(
    const float* __restrict__ pos, const float* __restrict__ x, const int* __restrict__ y,
    const float* __restrict__ be1, const float* __restrict__ be2,
    const float* __restrict__ b1,  const float* __restrict__ b2,
    const ushort* __restrict__ WT1, const ushort* __restrict__ WT2,
    const ushort* __restrict__ WT3, const ushort* __restrict__ WT4,
    const int* __restrict__ counts, float* __restrict__ gsums, int* __restrict__ done,
    const float* __restrict__ prior, float* __restrict__ out) {
  __shared__ ushort actbuf[TP * 264];       // 33792 B: act1 [64][256+8], later act3
  __shared__ ushort chunk2[2][TP * 136];    // 2 x 17408 B: A0 (stride 40) -> act2 chunks, dbuf
  __shared__ float  part[8 * TP];           // 2048 B
  __shared__ float  inv_norm[TP];
  __shared__ float  lbl_eff[TP];
  __shared__ int    lbl[TP];
  __shared__ float  invn[NCLS];
  __shared__ int    is_last;

  const int tid  = threadIdx.x;
  const int wave = tid >> 6, lane = tid & 63;
  const int quad = lane >> 4, mrow = lane & 15;
  const long p0 = (long)blockIdx.x * TP;   // 40000 % 64 == 0: block never spans batches
  const int bb = (int)(p0 / NPB);
  const int n0 = (int)(p0 % NPB);
  const f32x4 zero = {0.f, 0.f, 0.f, 0.f};

  // ---- stage A0 = [x(4) | pos(3) | 0...] bf16, stride 40, into chunk2[0] ----
  for (int i = tid; i < TP * 40; i += 512) {
    int r = i / 40, k = i - r * 40;
    float v = 0.f;
    if (k < 4)      v = x[(bb * 4 + k) * NPB + n0 + r];
    else if (k < 7) v = pos[(p0 + r) * 3 + (k - 4)];
    chunk2[0][r * 40 + k] = f2bf(v);
  }
  if (tid < TP) lbl[tid] = y[p0 + tid];
  __syncthreads();                                            // B1

  // ---- L1: [64x32] @ WT1[256][32]^T -> act1; wave cols wave*32 + nt*16 ----
  {
    f32x4 acc1[4][2];
    #pragma unroll
    for (int mt = 0; mt < 4; mt++) { acc1[mt][0] = zero; acc1[mt][1] = zero; }
    const int kl = quad << 3;
    bf16x8 af[4], bw[2];
    #pragma unroll
    for (int mt = 0; mt < 4; mt++)
      af[mt] = *(const bf16x8*)(&chunk2[0][0] + (mt * 16 + mrow) * 40 + kl);
    #pragma unroll
    for (int nt = 0; nt < 2; nt++)
      bw[nt] = *(const bf16x8*)(WT1 + (wave * 32 + nt * 16 + mrow) * 32 + kl);
    #pragma unroll
    for (int nt = 0; nt < 2; nt++)
      #pragma unroll
      for (int mt = 0; mt < 4; mt++)
        acc1[mt][nt] = __builtin_amdgcn_mfma_f32_16x16x32_bf16(af[mt], bw[nt], acc1[mt][nt], 0, 0, 0);
    #pragma unroll
    for (int nt = 0; nt < 2; nt++) {
      int n = wave * 32 + nt * 16 + mrow;
      float bv = be1[n];
      #pragma unroll
      for (int mt = 0; mt < 4; mt++)
        #pragma unroll
        for (int r = 0; r < 4; r++)
          actbuf[(mt * 16 + quad * 4 + r) * 264 + n] = f2bf(fmaxf(acc1[mt][nt][r] + bv, 0.f));
    }
  }
  __syncthreads();                                            // B2 (also covers A0 readers)

  // ---- fused L2+L3, double-buffered chunks: ONE barrier per chunk ----
  // Safety: a wave at write(c) has passed barrier(c-1), which all waves reach only
  // after finishing their L3(c-2) reads of the same buffer.
  f32x4 acc3[4][2];
  #pragma unroll
  for (int mt = 0; mt < 4; mt++) { acc3[mt][0] = zero; acc3[mt][1] = zero; }

  for (int c = 0; c < 4; c++) {
    ushort* cb = &chunk2[c & 1][0];
    // L2: wave computes act2 chunk-local cols [wave*16, +16)
    f32x4 acc2[4];
    #pragma unroll
    for (int mt = 0; mt < 4; mt++) acc2[mt] = zero;
    #pragma unroll
    for (int ks = 0; ks < 8; ks++) {
      const int kl = ks * 32 + (quad << 3);
      bf16x8 af[4];
      #pragma unroll
      for (int mt = 0; mt < 4; mt++)
        af[mt] = *(const bf16x8*)(actbuf + (mt * 16 + mrow) * 264 + kl);
      bf16x8 bw = *(const bf16x8*)(WT2 + (long)(c * 128 + wave * 16 + mrow) * 256 + kl);
      #pragma unroll
      for (int mt = 0; mt < 4; mt++)
        acc2[mt] = __builtin_amdgcn_mfma_f32_16x16x32_bf16(af[mt], bw, acc2[mt], 0, 0, 0);
    }
    {
      int lc = wave * 16 + mrow;            // chunk-local col
      float bv = be2[c * 128 + lc];
      #pragma unroll
      for (int mt = 0; mt < 4; mt++)
        #pragma unroll
        for (int r = 0; r < 4; r++)
          cb[(mt * 16 + quad * 4 + r) * 136 + lc] = f2bf(fmaxf(acc2[mt][r] + bv, 0.f));
    }
    __syncthreads();                                          // B3..B6
    // L3 accumulate over this chunk's 128 k values; wave cols wave*32 + nt*16
    #pragma unroll
    for (int ks = 0; ks < 4; ks++) {
      const int kl = ks * 32 + (quad << 3);
      bf16x8 af[4], bw[2];
      #pragma unroll
      for (int mt = 0; mt < 4; mt++)
        af[mt] = *(const bf16x8*)(cb + (mt * 16 + mrow) * 136 + kl);
      #pragma unroll
      for (int nt = 0; nt < 2; nt++)
        bw[nt] = *(const bf16x8*)(WT3 + (long)(wave * 32 + nt * 16 + mrow) * 512 + c * 128 + kl);
      #pragma unroll
      for (int nt = 0; nt < 2; nt++)
        #pragma unroll
        for (int mt = 0; mt < 4; mt++)
          acc3[mt][nt] = __builtin_amdgcn_mfma_f32_16x16x32_bf16(af[mt], bw[nt], acc3[mt][nt], 0, 0, 0);
    }
  }

  // ---- L3 epilogue -> act3 into actbuf ----
  // No barrier needed before these writes: last actbuf reads were in L2(3), pre-B6.
  #pragma unroll
  for (int nt = 0; nt < 2; nt++) {
    int n = wave * 32 + nt * 16 + mrow;
    float bv = b1[n];
    #pragma unroll
    for (int mt = 0; mt < 4; mt++)
      #pragma unroll
      for (int r = 0; r < 4; r++)
        actbuf[(mt * 16 + quad * 4 + r) * 264 + n] = f2bf(fmaxf(acc3[mt][nt][r] + bv, 0.f));
  }
  __syncthreads();                                            // B7

  // ---- L4: wave col = wave*16 + mrow; feat stays in registers ----
  f32x4 acc4[4];
  #pragma unroll
  for (int mt = 0; mt < 4; mt++) acc4[mt] = zero;
  #pragma unroll
  for (int ks = 0; ks < 8; ks++) {
    const int kl = ks * 32 + (quad << 3);
    bf16x8 af[4];
    #pragma unroll
    for (int mt = 0; mt < 4; mt++)
      af[mt] = *(const bf16x8*)(actbuf + (mt * 16 + mrow) * 264 + kl);
    bf16x8 bw = *(const bf16x8*)(WT4 + (long)(wave * 16 + mrow) * 256 + kl);
    #pragma unroll
    for (int mt = 0; mt < 4; mt++)
      acc4[mt] = __builtin_amdgcn_mfma_f32_16x16x32_bf16(af[mt], bw, acc4[mt], 0, 0, 0);
  }
  const int col = wave * 16 + mrow;
  float val[4][4];
  {
    float bv = b2[col];
    #pragma unroll
    for (int mt = 0; mt < 4; mt++)
      #pragma unroll
      for (int r = 0; r < 4; r++)
        val[mt][r] = fmaxf(acc4[mt][r] + bv, 0.f);
  }

  // ---- row-norm partials via quad shfl ----
  #pragma unroll
  for (int mt = 0; mt < 4; mt++)
    #pragma unroll
    for (int r = 0; r < 4; r++) {
      float s = val[mt][r] * val[mt][r];
      s += __shfl_xor(s, 1);  s += __shfl_xor(s, 2);
      s += __shfl_xor(s, 4);  s += __shfl_xor(s, 8);
      if (mrow == 0) part[wave * TP + mt * 16 + quad * 4 + r] = s;
    }
  __syncthreads();                                            // B8
  if (tid < TP) {
    float ss = 0.f;
    #pragma unroll
    for (int w = 0; w < 8; w++) ss += part[w * TP + tid];
    inv_norm[tid] = 1.f / fmaxf(sqrtf(ss), 1e-12f);
    int l = lbl[tid];
    lbl_eff[tid] = (counts[l] >= 256) ? (float)l : -1.f;   // MIN_PTS gate
  }
  __syncthreads();                                            // B9

  // ---- store current_prior from regs + per-class sums ----
  float a[NCLS];
  #pragma unroll
  for (int cc = 0; cc < NCLS; cc++) a[cc] = 0.f;
  #pragma unroll
  for (int mt = 0; mt < 4; mt++)
    #pragma unroll
    for (int r = 0; r < 4; r++) {
      int R = mt * 16 + quad * 4 + r;
      float vn = val[mt][r] * inv_norm[R];
      out[(p0 + R) * 129 + col] = vn;
      int cls = lbl[R];
      #pragma unroll
      for (int cc = 0; cc < NCLS; cc++) a[cc] += (cls == cc) ? vn : 0.f;
    }
  if (tid < TP) out[(p0 + tid) * 129 + 128] = lbl_eff[tid];
  #pragma unroll
  for (int cc = 0; cc < NCLS; cc++) {
    a[cc] += __shfl_xor(a[cc], 16);
    a[cc] += __shfl_xor(a[cc], 32);
  }
  if (quad == 0)
    #pragma unroll
    for (int cc = 0; cc < NCLS; cc++) atomicAdd(&gsums[cc * 128 + col], a[cc]);

  // ---- last block finalizes the EMA prior (saves a dispatch) ----
  // Ordering: __syncthreads drains vmcnt(0) -> this block's gsums atomics have
  // completed at the device coherence point before the done increment.
  __syncthreads();                                            // B10
  if (tid == 0) {
    int old = atomicAdd(done, 1);
    is_last = (old == NBLK - 1);
  }
  __syncthreads();
  if (!is_last) return;

  float* vbuf = (float*)actbuf;            // actbuf dead; 6656 B needed
  for (int i = tid; i < NCLS * 128; i += 512) {
    float g = atomicAdd(&gsums[i], 0.f);   // coherent device-scope read
    int cls = i >> 7;
    int cnt = counts[cls];
    float mean = g / fmaxf((float)cnt, 1.f);
    float pr = prior[i];
    float cur = (cnt >= 256) ? mean : pr;
    vbuf[i] = 0.999f * pr + 0.001f * cur;
  }
  __syncthreads();
  if (tid < NCLS) {
    float s = 0.f;
    for (int c = 0; c < 128; c++) { float t = vbuf[tid * 128 + c]; s += t * t; }
    invn[tid] = 1.f / fmaxf(sqrtf(s), 1e-12f);
  }
  __syncthreads();
  for (int i = tid; i < NCLS * 128; i += 512)
    out[(long)P_TOTAL * 129 + i] = vbuf[i] * invn[i >> 7];
}

extern "C" void kernel_launch(void* const* d_in, const int* in_sizes, int n_in,
                              void* d_out, int out_size, void* d_ws, size_t ws_size,
                              hipStream_t stream) {
  const float* pos   = (const float*)d_in[0];
  const float* x     = (const float*)d_in[1];
  const int*   y     = (const int*)  d_in[2];
  const float* We1   = (const float*)d_in[3];
  const float* be1   = (const float*)d_in[4];
  const float* We2   = (const float*)d_in[5];
  const float* be2   = (const float*)d_in[6];
  const float* W1    = (const float*)d_in[7];
  const float* b1    = (const float*)d_in[8];
  const float* W2    = (const float*)d_in[9];
  const float* b2    = (const float*)d_in[10];
  const float* prior = (const float*)d_in[11];
  float* out = (float*)d_out;

  char* ws = (char*)d_ws;
  int*    counts = (int*)   (ws + 0);        //    64 B
  float*  gsums  = (float*) (ws + 256);      //  6656 B
  int*    done   = (int*)   (ws + 7168);     //     4 B
  ushort* WT1    = (ushort*)(ws + 8192);     // 16384 B  [256][32]
  ushort* WT2    = (ushort*)(ws + 24576);    // 262144 B [512][256]
  ushort* WT3    = (ushort*)(ws + 286720);   // 262144 B [256][512]
  ushort* WT4    = (ushort*)(ws + 548864);   // 65536 B  [128][256]

  hipMemsetAsync(ws, 0, 8192, stream);       // counts + gsums + done
  prep_all_kernel<<<416, 256, 0, stream>>>(We1, We2, W1, W2, y, WT1, WT2, WT3, WT4, counts);
  main_kernel    <<<NBLK, 512, 0, stream>>>(pos, x, y, be1, be2, b1, b2,
                                            WT1, WT2, WT3, WT4, counts, gsums, done, prior, out);
}